// Round 6
// baseline (365.533 us; speedup 1.0000x reference)
//
#include <hip/hip_runtime.h>
#include <hip/hip_bf16.h>

// Transformer block fwd (B=2,T=2048,C=1024,H=16,D=64,HID=4096), bf16 MFMA compute.
// Round 6: 2-phase double-buffered staging (T3-minimum) for attn + low-occupancy GEMMs,
//          split-K=2 MLP2 (+addp fold), bijective XCD swizzle on GEMM grids.

#define B_ 2
#define T_ 2048
#define C_ 1024
#define H_ 16
#define D_ 64
#define HID_ 4096
#define M_ 4096  // B*T

typedef __bf16 bf16x8 __attribute__((ext_vector_type(8)));
typedef float f32x4 __attribute__((ext_vector_type(4)));
using bf16 = __hip_bfloat16;

static __device__ __forceinline__ f32x4 mfma16(bf16x8 a, bf16x8 b, f32x4 c) {
  return __builtin_amdgcn_mfma_f32_16x16x32_bf16(a, b, c, 0, 0, 0);
}

// async global->LDS, 16B per lane; LDS dest = wave-uniform base + lane*16
static __device__ __forceinline__ void gload16(const bf16* g, bf16* l) {
  __builtin_amdgcn_global_load_lds(
      (const __attribute__((address_space(1))) unsigned int*)g,
      (__attribute__((address_space(3))) unsigned int*)l, 16, 0, 0);
}

// ---- weight convert + transpose: in f32 [K][N] -> out bf16 [N][K] ----
__global__ __launch_bounds__(256) void cvt_transpose(const float* __restrict__ in,
                                                     bf16* __restrict__ out, int K, int N) {
  __shared__ float tile[32][33];
  int tid = threadIdx.x, tx = tid & 31, ty = tid >> 5;
  int n0 = blockIdx.x * 32, k0 = blockIdx.y * 32;
#pragma unroll
  for (int i = 0; i < 4; ++i) {
    int r = ty + i * 8;
    tile[r][tx] = in[(size_t)(k0 + r) * N + n0 + tx];
  }
  __syncthreads();
#pragma unroll
  for (int i = 0; i < 4; ++i) {
    int r = ty + i * 8;
    out[(size_t)(n0 + r) * K + k0 + tx] = __float2bfloat16(tile[tx][r]);
  }
}

// ---- pack q/k/v bias into one 3072 vector ----
__global__ __launch_bounds__(256) void pack_bias(const float* __restrict__ q,
                                                 const float* __restrict__ k,
                                                 const float* __restrict__ v,
                                                 float* __restrict__ o) {
  int i = blockIdx.x * 256 + threadIdx.x;
  o[i] = i < 1024 ? q[i] : (i < 2048 ? k[i - 1024] : v[i - 2048]);
}

// ---- RMSNorm: x f32 [rows][1024] -> out bf16 ----
__global__ __launch_bounds__(256) void rmsnorm_kernel(const float* __restrict__ x,
                                                      const float* __restrict__ w,
                                                      bf16* __restrict__ out) {
  int row = blockIdx.x, tid = threadIdx.x;
  float4 v = ((const float4*)(x + (size_t)row * C_))[tid];
  float ss = v.x * v.x + v.y * v.y + v.z * v.z + v.w * v.w;
#pragma unroll
  for (int d = 1; d < 64; d <<= 1) ss += __shfl_xor(ss, d);
  __shared__ float wsum[4];
  if ((tid & 63) == 0) wsum[tid >> 6] = ss;
  __syncthreads();
  float tot = wsum[0] + wsum[1] + wsum[2] + wsum[3];
  float r = rsqrtf(tot * (1.0f / C_) + 1e-5f);
  float4 wv = ((const float4*)w)[tid];
  bf16* o = out + (size_t)row * C_ + tid * 4;
  o[0] = __float2bfloat16(v.x * wv.x * r);
  o[1] = __float2bfloat16(v.y * wv.y * r);
  o[2] = __float2bfloat16(v.z * wv.z * r);
  o[3] = __float2bfloat16(v.w * wv.w * r);
}

// ---- out[i] += p[i], float4 grid-stride ----
__global__ __launch_bounds__(256) void addp_kernel(float* __restrict__ out,
                                                   const float* __restrict__ p, int n4) {
  int i = blockIdx.x * 256 + threadIdx.x;
  int stride = gridDim.x * 256;
  for (; i < n4; i += stride) {
    float4 a = ((const float4*)out)[i];
    float4 b = ((const float4*)p)[i];
    a.x += b.x; a.y += b.y; a.z += b.z; a.w += b.w;
    ((float4*)out)[i] = a;
  }
}

// ---- GEMM: C[M,N] = A[M,K] @ Bt[N,K]^T + bias. 128x128 tile, BK=64, 4 waves.
// DBUF=1: 2-phase double-buffered staging (issue next tile, compute cur, one barrier).
// SK: split-K via blockIdx.z; z=0 writes EPI result, z>0 writes raw f32 partial to paux.
// EPI 0: fused-QKV scatter: q->bf16 (B,H,T,D); k->bf16+f32 dup; v->bf16 V^T + f32 dup
// EPI 1: f32 out = acc + bias + res
// EPI 2: bf16 out = gelu(acc + bias)
template <int EPI, int DBUF, int SK>
__global__ __launch_bounds__(256) void gemm_kernel(
    const bf16* __restrict__ A, const bf16* __restrict__ Bt, const float* __restrict__ bias,
    bf16* __restrict__ bfout, float* __restrict__ fout, const float* __restrict__ res,
    bf16* __restrict__ vtb, float* __restrict__ paux, int M, int N, int K) {
  __shared__ bf16 Al[(DBUF ? 2 : 1) * 128 * 64];
  __shared__ bf16 Bl[(DBUF ? 2 : 1) * 128 * 64];
  int tid = threadIdx.x, w = tid >> 6, l = tid & 63;
  int g = l >> 4, c = l & 15;
  // bijective XCD-chunk swizzle (nwg % 8 == 0 for all launches here)
  int nwg = gridDim.x * gridDim.y;
  int bidl = blockIdx.y * gridDim.x + blockIdx.x;
  int wgid = (bidl & 7) * (nwg >> 3) + (bidl >> 3);
  int bx = wgid % gridDim.x, by = wgid / gridDim.x;
  int m0 = by * 128, n0 = bx * 128;
  int wm = (w >> 1) * 64, wn = (w & 1) * 64;
  int Kc = K / SK;
  int kbase = (SK > 1) ? (int)blockIdx.z * Kc : 0;
  int KT = Kc >> 6;
  int lrow = l >> 3, lcol = (l & 7) * 8;

  const bf16* gA = A + (size_t)(m0 + w * 32 + lrow) * K + kbase + lcol;
  const bf16* gB = Bt + (size_t)(n0 + w * 32 + lrow) * K + kbase + lcol;

  auto stage = [&](int kt, int buf) {
#pragma unroll
    for (int i = 0; i < 4; ++i) {
      gload16(gA + (size_t)i * 8 * K + kt * 64, Al + buf * 8192 + (w * 4 + i) * 512);
      gload16(gB + (size_t)i * 8 * K + kt * 64, Bl + buf * 8192 + (w * 4 + i) * 512);
    }
  };
  auto compute = [&](int buf, f32x4 (&acc)[4][4]) {
#pragma unroll
    for (int ch = 0; ch < 2; ++ch) {
      bf16x8 af[4], bfr[4];
#pragma unroll
      for (int f = 0; f < 4; ++f)
        af[f] = *(const bf16x8*)&Al[buf * 8192 + (wm + f * 16 + c) * 64 + ch * 32 + g * 8];
#pragma unroll
      for (int f = 0; f < 4; ++f)
        bfr[f] = *(const bf16x8*)&Bl[buf * 8192 + (wn + f * 16 + c) * 64 + ch * 32 + g * 8];
#pragma unroll
      for (int mf = 0; mf < 4; ++mf)
#pragma unroll
        for (int nf = 0; nf < 4; ++nf) acc[mf][nf] = mfma16(af[mf], bfr[nf], acc[mf][nf]);
    }
  };

  f32x4 acc[4][4] = {};
  if (DBUF) {
    stage(0, 0);
    __syncthreads();
    for (int kt = 0; kt < KT; ++kt) {
      int cur = kt & 1;
      if (kt + 1 < KT) stage(kt + 1, cur ^ 1);
      compute(cur, acc);
      __syncthreads();
    }
  } else {
    for (int kt = 0; kt < KT; ++kt) {
      stage(kt, 0);
      __syncthreads();
      compute(0, acc);
      __syncthreads();
    }
  }

#pragma unroll
  for (int mf = 0; mf < 4; ++mf) {
#pragma unroll
    for (int nf = 0; nf < 4; ++nf) {
      int gn = n0 + wn + nf * 16 + c;
      float bv = bias ? bias[gn] : 0.f;
#pragma unroll
      for (int r = 0; r < 4; ++r) {
        int gm = m0 + wm + mf * 16 + g * 4 + r;
        float vr = acc[mf][nf][r];
        float v = vr + bv;
        if (SK > 1 && blockIdx.z > 0) {
          paux[(size_t)gm * N + gn] = vr;
        } else if (EPI == 0) {
          int part = gn >> 10, wi = gn & 1023, hh = wi >> 6, d = wi & 63;
          int b_ = gm >> 11, t = gm & 2047;
          size_t idx = ((size_t)(b_ * H_ + hh) * T_ + t) * D_ + d;
          if (part == 2) {
            vtb[((size_t)(b_ * H_ + hh) * D_ + d) * T_ + t] = __float2bfloat16(v);
            fout[(size_t)2 * 4194304 + idx] = v;
          } else {
            bfout[(size_t)part * 4194304 + idx] = __float2bfloat16(v);
            if (part) fout[(size_t)part * 4194304 + idx] = v;
          }
        } else if (EPI == 1) {
          size_t idx = (size_t)gm * N + gn;
          fout[idx] = v + res[idx];
        } else {
          size_t idx = (size_t)gm * N + gn;
          float gl = 0.5f * v * (1.0f + erff(v * 0.70710678118f));
          bfout[idx] = __float2bfloat16(gl);
        }
      }
    }
  }
}

// ---- Flash attention (causal): shared-LDS KV staging, double-buffered (2-phase),
// 128-row q-tile, 4 waves. Q,K bf16 (B,H,T,D), Vt bf16 (B,H,D,T).
__global__ __launch_bounds__(256, 2) void attn_kernel(const bf16* __restrict__ Q,
                                                      const bf16* __restrict__ Kb,
                                                      const bf16* __restrict__ Vt,
                                                      bf16* __restrict__ ctx) {
  constexpr int LDP = 136;
  __shared__ bf16 Kl[2][64 * 64];
  __shared__ bf16 Vl[2][64 * 64];
  __shared__ bf16 Pl[4][16 * LDP];
  int tid = threadIdx.x, w = tid >> 6, l = tid & 63, g = l >> 4, c = l & 15;
  int bid = blockIdx.x;
  int qt = 15 - (bid >> 5);  // LPT: heavy q-tiles first
  int bh = bid & 31;         // same-bh stride 32 -> same XCD -> K/V L2 locality
  int qbase = qt * 128 + w * 32;
  const bf16* Qh = Q + (size_t)bh * T_ * D_;
  const bf16* Kh = Kb + (size_t)bh * T_ * D_;
  const bf16* Vh = Vt + (size_t)bh * T_ * D_;  // [D][T]

  int srow = l >> 3;
  int sce = ((l & 7) * 8) ^ (srow << 3);  // pre-swizzled source col (involution w/ read)
  int cswz = (c & 7) << 3;                // read-side swizzle

  auto stage = [&](int ti, int buf) {
#pragma unroll
    for (int i = 0; i < 2; ++i) {
      int row = i * 32 + w * 8 + srow;
      gload16(&Kh[(size_t)(ti * 64 + row) * D_ + sce], &Kl[buf][i * 2048 + w * 512]);
      gload16(&Vh[(size_t)row * T_ + ti * 64 + sce], &Vl[buf][i * 2048 + w * 512]);
    }
  };

  int NT = 2 * qt + 2;
  stage(0, 0);

  // Q fragments: 32 rows/wave = 2 frags x 2 k-chunks (loads fly with stage(0))
  bf16x8 aq[2][2];
#pragma unroll
  for (int qf = 0; qf < 2; ++qf)
#pragma unroll
    for (int ch = 0; ch < 2; ++ch)
      aq[qf][ch] = *(const bf16x8*)&Qh[(size_t)(qbase + qf * 16 + c) * D_ + ch * 32 + g * 8];

  f32x4 o[2][4] = {};
  float mrun[2][4], lrun[2][4];
#pragma unroll
  for (int qf = 0; qf < 2; ++qf)
#pragma unroll
    for (int r = 0; r < 4; ++r) { mrun[qf][r] = -1e30f; lrun[qf][r] = 0.f; }

  __syncthreads();  // tile 0 staged

  for (int ti = 0; ti < NT; ++ti) {
    int cur = ti & 1;
    int kv0 = ti * 64;
    if (ti + 1 < NT) stage(ti + 1, cur ^ 1);  // latency hides under this tile's work

    // K fragments (shared across qf) and QK^T
    bf16x8 bk[4][2];
#pragma unroll
    for (int kb = 0; kb < 4; ++kb)
#pragma unroll
      for (int ch = 0; ch < 2; ++ch)
        bk[kb][ch] = *(const bf16x8*)&Kl[cur][(kb * 16 + c) * 64 + ((ch * 32 + g * 8) ^ cswz)];
    f32x4 sf[2][4];
#pragma unroll
    for (int qf = 0; qf < 2; ++qf)
#pragma unroll
      for (int kb = 0; kb < 4; ++kb) {
        f32x4 t = {};
        t = mfma16(aq[qf][0], bk[kb][0], t);
        t = mfma16(aq[qf][1], bk[kb][1], t);
        sf[qf][kb] = t;
      }
    // V fragments (shared across qf)
    bf16x8 bvv[4][2];
#pragma unroll
    for (int db = 0; db < 4; ++db)
#pragma unroll
      for (int ck = 0; ck < 2; ++ck)
        bvv[db][ck] = *(const bf16x8*)&Vl[cur][(db * 16 + c) * 64 + ((ck * 32 + g * 8) ^ cswz)];

    float s[2][4][4];
#pragma unroll
    for (int qf = 0; qf < 2; ++qf)
#pragma unroll
      for (int kb = 0; kb < 4; ++kb)
#pragma unroll
        for (int r = 0; r < 4; ++r) s[qf][kb][r] = sf[qf][kb][r] * 0.125f;
    if (kv0 + 63 > qbase) {  // wave-uniform; fully-masked tiles safe (exp->0)
#pragma unroll
      for (int qf = 0; qf < 2; ++qf)
#pragma unroll
        for (int kb = 0; kb < 4; ++kb)
#pragma unroll
          for (int r = 0; r < 4; ++r) {
            int qi = qbase + qf * 16 + g * 4 + r;
            int kv = kv0 + kb * 16 + c;
            if (kv > qi) s[qf][kb][r] = -1e30f;
          }
    }
    // online softmax (row = 16 lanes sharing g)
#pragma unroll
    for (int qf = 0; qf < 2; ++qf)
#pragma unroll
      for (int r = 0; r < 4; ++r) {
        float tm = fmaxf(fmaxf(s[qf][0][r], s[qf][1][r]), fmaxf(s[qf][2][r], s[qf][3][r]));
#pragma unroll
        for (int d = 1; d < 16; d <<= 1) tm = fmaxf(tm, __shfl_xor(tm, d));
        float mn = fmaxf(mrun[qf][r], tm);
        float al = __expf(mrun[qf][r] - mn);
        mrun[qf][r] = mn;
        float asum = 0.f;
#pragma unroll
        for (int kb = 0; kb < 4; ++kb) {
          float pv = __expf(s[qf][kb][r] - mn);
          s[qf][kb][r] = pv;
          asum += pv;
        }
#pragma unroll
        for (int d = 1; d < 16; d <<= 1) asum += __shfl_xor(asum, d);
        lrun[qf][r] = lrun[qf][r] * al + asum;
#pragma unroll
        for (int db = 0; db < 4; ++db) o[qf][db][r] *= al;
      }

    // P (C-layout) -> per-wave LDS -> A-frag layout; PV
#pragma unroll
    for (int qf = 0; qf < 2; ++qf) {
#pragma unroll
      for (int kb = 0; kb < 4; ++kb)
#pragma unroll
        for (int r = 0; r < 4; ++r)
          Pl[w][(g * 4 + r) * LDP + kb * 16 + c] = __float2bfloat16(s[qf][kb][r]);
      bf16x8 pa0 = *(const bf16x8*)&Pl[w][c * LDP + g * 8];
      bf16x8 pa1 = *(const bf16x8*)&Pl[w][c * LDP + 32 + g * 8];
#pragma unroll
      for (int db = 0; db < 4; ++db) {
        o[qf][db] = mfma16(pa0, bvv[db][0], o[qf][db]);
        o[qf][db] = mfma16(pa1, bvv[db][1], o[qf][db]);
      }
    }
    __syncthreads();  // next tile staged + all waves done with cur
  }

  int b_ = bh >> 4, hh = bh & 15;
#pragma unroll
  for (int qf = 0; qf < 2; ++qf)
#pragma unroll
    for (int r = 0; r < 4; ++r) {
      float inv = 1.0f / lrun[qf][r];
#pragma unroll
      for (int db = 0; db < 4; ++db)
        ctx[(size_t)(b_ * T_ + qbase + qf * 16 + g * 4 + r) * C_ + hh * D_ + db * 16 + c] =
            __float2bfloat16(o[qf][db][r] * inv);
    }
}

extern "C" void kernel_launch(void* const* d_in, const int* in_sizes, int n_in, void* d_out,
                              int out_size, void* d_ws, size_t ws_size, hipStream_t stream) {
  const float* x = (const float*)d_in[0];
  const float* anw = (const float*)d_in[2];
  const float* mnw = (const float*)d_in[3];
  const float* q_w = (const float*)d_in[4];
  const float* q_b = (const float*)d_in[5];
  const float* k_w = (const float*)d_in[6];
  const float* k_b = (const float*)d_in[7];
  const float* v_w = (const float*)d_in[8];
  const float* v_b = (const float*)d_in[9];
  const float* o_w = (const float*)d_in[10];
  const float* o_b = (const float*)d_in[11];
  const float* w1 = (const float*)d_in[12];
  const float* b1 = (const float*)d_in[13];
  const float* w2 = (const float*)d_in[14];
  const float* b2 = (const float*)d_in[15];
  float* out = (float*)d_out;
  char* ws = (char*)d_ws;

  // ws layout (<= 83886080 B, reused):
  bf16* qkvT = (bf16*)(ws + 0);          // 6 MB [3072][1024]; dead after QKV gemm
  bf16* owT = (bf16*)(ws + 6291456);     // 2 MB; dead after o-proj
  bf16* w1T = (bf16*)(ws + 8388608);     // 8 MB
  bf16* w2T = (bf16*)(ws + 16777216);    // 8 MB
  bf16* h = (bf16*)(ws + 25165824);      // 8 MB  (also m)
  bf16* qb = (bf16*)(ws + 33554432);     // 8 MB
  bf16* kb = (bf16*)(ws + 41943040);     // 8 MB
  bf16* vtb = (bf16*)(ws + 58720256);    // 8 MB  V^T (B,H,D,T), by QKV EPI0
  bf16* ctx = (bf16*)(ws + 67108864);    // 8 MB
  float* x2 = (float*)(ws + 33554432);   // 16 MB over qb+kb (dead after attention)
  bf16* m = h;                           // reuse
  bf16* hid = (bf16*)(ws + 50331648);    // 32 MB, ends 83886080 (dead regions reused)
  float* qkvb = (float*)(ws + 75497472); // 12 KB (inside hid span; dead before MLP1)
  float* p1 = (float*)(ws + 0);          // 16 MB MLP2 split-K partial (qkvT/owT/w1T dead)

  cvt_transpose<<<dim3(32, 32), 256, 0, stream>>>(q_w, qkvT, 1024, 1024);
  cvt_transpose<<<dim3(32, 32), 256, 0, stream>>>(k_w, qkvT + 1048576, 1024, 1024);
  cvt_transpose<<<dim3(32, 32), 256, 0, stream>>>(v_w, qkvT + 2097152, 1024, 1024);
  cvt_transpose<<<dim3(32, 32), 256, 0, stream>>>(o_w, owT, 1024, 1024);
  cvt_transpose<<<dim3(128, 32), 256, 0, stream>>>(w1, w1T, 1024, 4096);
  cvt_transpose<<<dim3(32, 128), 256, 0, stream>>>(w2, w2T, 4096, 1024);
  pack_bias<<<12, 256, 0, stream>>>(q_b, k_b, v_b, qkvb);

  rmsnorm_kernel<<<4096, 256, 0, stream>>>(x, anw, h);

  // fused QKV: C[4096][3072]; v written transposed for attention
  gemm_kernel<0, 0, 1><<<dim3(24, 32), 256, 0, stream>>>(h, qkvT, qkvb, qb, out, nullptr,
                                                         vtb, nullptr, 4096, 3072, 1024);

  attn_kernel<<<512, 256, 0, stream>>>(qb, kb, vtb, ctx);

  gemm_kernel<1, 1, 1><<<dim3(8, 32), 256, 0, stream>>>(ctx, owT, o_b, nullptr, x2, x,
                                                        nullptr, nullptr, 4096, 1024, 1024);

  rmsnorm_kernel<<<4096, 256, 0, stream>>>(x2, mnw, m);

  gemm_kernel<2, 0, 1><<<dim3(32, 32), 256, 0, stream>>>(m, w1T, b1, hid, nullptr, nullptr,
                                                         nullptr, nullptr, 4096, 4096, 1024);
  // MLP2 split-K=2: z=0 -> out (+bias+residual), z=1 -> raw partial p1; then fold.
  gemm_kernel<1, 1, 2><<<dim3(8, 32, 2), 256, 0, stream>>>(hid, w2T, b2, nullptr, out, x2,
                                                           nullptr, p1, 4096, 1024, 4096);
  addp_kernel<<<2048, 256, 0, stream>>>(out, p1, 1048576);
}

// Round 7
// 341.196 us; speedup vs baseline: 1.0713x; 1.0713x over previous
//
#include <hip/hip_runtime.h>
#include <hip/hip_bf16.h>

// Transformer block fwd (B=2,T=2048,C=1024,H=16,D=64,HID=4096), bf16 MFMA compute.
// Round 7: attention with SWAPPED QK^T (mfma(K,Q)) -> lane-local P rows: softmax
//          shuffles 64->8/tile, P writes 64 scalar -> 8 ds_write_b64. GEMMs as R6.

#define B_ 2
#define T_ 2048
#define C_ 1024
#define H_ 16
#define D_ 64
#define HID_ 4096
#define M_ 4096  // B*T

typedef __bf16 bf16x8 __attribute__((ext_vector_type(8)));
typedef float f32x4 __attribute__((ext_vector_type(4)));
using bf16 = __hip_bfloat16;

static __device__ __forceinline__ f32x4 mfma16(bf16x8 a, bf16x8 b, f32x4 c) {
  return __builtin_amdgcn_mfma_f32_16x16x32_bf16(a, b, c, 0, 0, 0);
}

// async global->LDS, 16B per lane; LDS dest = wave-uniform base + lane*16
static __device__ __forceinline__ void gload16(const bf16* g, bf16* l) {
  __builtin_amdgcn_global_load_lds(
      (const __attribute__((address_space(1))) unsigned int*)g,
      (__attribute__((address_space(3))) unsigned int*)l, 16, 0, 0);
}

static __device__ __forceinline__ unsigned short bfbits(float x) {
  __hip_bfloat16 h = __float2bfloat16(x);
  return *(unsigned short*)&h;
}

// ---- weight convert + transpose: in f32 [K][N] -> out bf16 [N][K] ----
__global__ __launch_bounds__(256) void cvt_transpose(const float* __restrict__ in,
                                                     bf16* __restrict__ out, int K, int N) {
  __shared__ float tile[32][33];
  int tid = threadIdx.x, tx = tid & 31, ty = tid >> 5;
  int n0 = blockIdx.x * 32, k0 = blockIdx.y * 32;
#pragma unroll
  for (int i = 0; i < 4; ++i) {
    int r = ty + i * 8;
    tile[r][tx] = in[(size_t)(k0 + r) * N + n0 + tx];
  }
  __syncthreads();
#pragma unroll
  for (int i = 0; i < 4; ++i) {
    int r = ty + i * 8;
    out[(size_t)(n0 + r) * K + k0 + tx] = __float2bfloat16(tile[tx][r]);
  }
}

// ---- pack q/k/v bias into one 3072 vector ----
__global__ __launch_bounds__(256) void pack_bias(const float* __restrict__ q,
                                                 const float* __restrict__ k,
                                                 const float* __restrict__ v,
                                                 float* __restrict__ o) {
  int i = blockIdx.x * 256 + threadIdx.x;
  o[i] = i < 1024 ? q[i] : (i < 2048 ? k[i - 1024] : v[i - 2048]);
}

// ---- RMSNorm: x f32 [rows][1024] -> out bf16 ----
__global__ __launch_bounds__(256) void rmsnorm_kernel(const float* __restrict__ x,
                                                      const float* __restrict__ w,
                                                      bf16* __restrict__ out) {
  int row = blockIdx.x, tid = threadIdx.x;
  float4 v = ((const float4*)(x + (size_t)row * C_))[tid];
  float ss = v.x * v.x + v.y * v.y + v.z * v.z + v.w * v.w;
#pragma unroll
  for (int d = 1; d < 64; d <<= 1) ss += __shfl_xor(ss, d);
  __shared__ float wsum[4];
  if ((tid & 63) == 0) wsum[tid >> 6] = ss;
  __syncthreads();
  float tot = wsum[0] + wsum[1] + wsum[2] + wsum[3];
  float r = rsqrtf(tot * (1.0f / C_) + 1e-5f);
  float4 wv = ((const float4*)w)[tid];
  bf16* o = out + (size_t)row * C_ + tid * 4;
  o[0] = __float2bfloat16(v.x * wv.x * r);
  o[1] = __float2bfloat16(v.y * wv.y * r);
  o[2] = __float2bfloat16(v.z * wv.z * r);
  o[3] = __float2bfloat16(v.w * wv.w * r);
}

// ---- out[i] += p[i], float4 grid-stride ----
__global__ __launch_bounds__(256) void addp_kernel(float* __restrict__ out,
                                                   const float* __restrict__ p, int n4) {
  int i = blockIdx.x * 256 + threadIdx.x;
  int stride = gridDim.x * 256;
  for (; i < n4; i += stride) {
    float4 a = ((const float4*)out)[i];
    float4 b = ((const float4*)p)[i];
    a.x += b.x; a.y += b.y; a.z += b.z; a.w += b.w;
    ((float4*)out)[i] = a;
  }
}

// ---- GEMM: C[M,N] = A[M,K] @ Bt[N,K]^T + bias. 128x128 tile, BK=64, 4 waves. ----
template <int EPI, int DBUF, int SK>
__global__ __launch_bounds__(256) void gemm_kernel(
    const bf16* __restrict__ A, const bf16* __restrict__ Bt, const float* __restrict__ bias,
    bf16* __restrict__ bfout, float* __restrict__ fout, const float* __restrict__ res,
    bf16* __restrict__ vtb, float* __restrict__ paux, int M, int N, int K) {
  __shared__ bf16 Al[(DBUF ? 2 : 1) * 128 * 64];
  __shared__ bf16 Bl[(DBUF ? 2 : 1) * 128 * 64];
  int tid = threadIdx.x, w = tid >> 6, l = tid & 63;
  int g = l >> 4, c = l & 15;
  int nwg = gridDim.x * gridDim.y;
  int bidl = blockIdx.y * gridDim.x + blockIdx.x;
  int wgid = (bidl & 7) * (nwg >> 3) + (bidl >> 3);
  int bx = wgid % gridDim.x, by = wgid / gridDim.x;
  int m0 = by * 128, n0 = bx * 128;
  int wm = (w >> 1) * 64, wn = (w & 1) * 64;
  int Kc = K / SK;
  int kbase = (SK > 1) ? (int)blockIdx.z * Kc : 0;
  int KT = Kc >> 6;
  int lrow = l >> 3, lcol = (l & 7) * 8;

  const bf16* gA = A + (size_t)(m0 + w * 32 + lrow) * K + kbase + lcol;
  const bf16* gB = Bt + (size_t)(n0 + w * 32 + lrow) * K + kbase + lcol;

  auto stage = [&](int kt, int buf) {
#pragma unroll
    for (int i = 0; i < 4; ++i) {
      gload16(gA + (size_t)i * 8 * K + kt * 64, Al + buf * 8192 + (w * 4 + i) * 512);
      gload16(gB + (size_t)i * 8 * K + kt * 64, Bl + buf * 8192 + (w * 4 + i) * 512);
    }
  };
  auto compute = [&](int buf, f32x4 (&acc)[4][4]) {
#pragma unroll
    for (int ch = 0; ch < 2; ++ch) {
      bf16x8 af[4], bfr[4];
#pragma unroll
      for (int f = 0; f < 4; ++f)
        af[f] = *(const bf16x8*)&Al[buf * 8192 + (wm + f * 16 + c) * 64 + ch * 32 + g * 8];
#pragma unroll
      for (int f = 0; f < 4; ++f)
        bfr[f] = *(const bf16x8*)&Bl[buf * 8192 + (wn + f * 16 + c) * 64 + ch * 32 + g * 8];
#pragma unroll
      for (int mf = 0; mf < 4; ++mf)
#pragma unroll
        for (int nf = 0; nf < 4; ++nf) acc[mf][nf] = mfma16(af[mf], bfr[nf], acc[mf][nf]);
    }
  };

  f32x4 acc[4][4] = {};
  if (DBUF) {
    stage(0, 0);
    __syncthreads();
    for (int kt = 0; kt < KT; ++kt) {
      int cur = kt & 1;
      if (kt + 1 < KT) stage(kt + 1, cur ^ 1);
      compute(cur, acc);
      __syncthreads();
    }
  } else {
    for (int kt = 0; kt < KT; ++kt) {
      stage(kt, 0);
      __syncthreads();
      compute(0, acc);
      __syncthreads();
    }
  }

#pragma unroll
  for (int mf = 0; mf < 4; ++mf) {
#pragma unroll
    for (int nf = 0; nf < 4; ++nf) {
      int gn = n0 + wn + nf * 16 + c;
      float bv = bias ? bias[gn] : 0.f;
#pragma unroll
      for (int r = 0; r < 4; ++r) {
        int gm = m0 + wm + mf * 16 + g * 4 + r;
        float vr = acc[mf][nf][r];
        float v = vr + bv;
        if (SK > 1 && blockIdx.z > 0) {
          paux[(size_t)gm * N + gn] = vr;
        } else if (EPI == 0) {
          int part = gn >> 10, wi = gn & 1023, hh = wi >> 6, d = wi & 63;
          int b_ = gm >> 11, t = gm & 2047;
          size_t idx = ((size_t)(b_ * H_ + hh) * T_ + t) * D_ + d;
          if (part == 2) {
            vtb[((size_t)(b_ * H_ + hh) * D_ + d) * T_ + t] = __float2bfloat16(v);
            fout[(size_t)2 * 4194304 + idx] = v;
          } else {
            bfout[(size_t)part * 4194304 + idx] = __float2bfloat16(v);
            if (part) fout[(size_t)part * 4194304 + idx] = v;
          }
        } else if (EPI == 1) {
          size_t idx = (size_t)gm * N + gn;
          fout[idx] = v + res[idx];
        } else {
          size_t idx = (size_t)gm * N + gn;
          float gl = 0.5f * v * (1.0f + erff(v * 0.70710678118f));
          bfout[idx] = __float2bfloat16(gl);
        }
      }
    }
  }
}

// ---- Flash attention (causal): shared-LDS KV staging (dbuf), SWAPPED QK^T.
// mfma(K,Q) -> S[k=g*4+r][q=c]: P rows lane-local; softmax reduce = in-lane + 2 shfl;
// P repack = 4 ds_write_b64 + 2 ds_read_b128 per qf. PV/output layout unchanged.
__global__ __launch_bounds__(256, 2) void attn_kernel(const bf16* __restrict__ Q,
                                                      const bf16* __restrict__ Kb,
                                                      const bf16* __restrict__ Vt,
                                                      bf16* __restrict__ ctx) {
  constexpr int LDP = 72;  // row 144B: b64 writes & b128 reads land 2-way (free)
  __shared__ bf16 Kl[2][64 * 64];
  __shared__ bf16 Vl[2][64 * 64];
  __shared__ bf16 Pl[4][2][16 * LDP];  // [wave][qf][q=c][k]
  __shared__ float alw[4][2][16];      // alpha / inv transpose scratch
  int tid = threadIdx.x, w = tid >> 6, l = tid & 63, g = l >> 4, c = l & 15;
  int bid = blockIdx.x;
  int qt = 15 - (bid >> 5);  // LPT: heavy q-tiles first
  int bh = bid & 31;         // same-bh stride 32 -> same XCD -> K/V L2 locality
  int qbase = qt * 128 + w * 32;
  const bf16* Qh = Q + (size_t)bh * T_ * D_;
  const bf16* Kh = Kb + (size_t)bh * T_ * D_;
  const bf16* Vh = Vt + (size_t)bh * T_ * D_;  // [D][T]

  int srow = l >> 3;
  int sce = ((l & 7) * 8) ^ (srow << 3);  // pre-swizzled source col (involution w/ read)
  int cswz = (c & 7) << 3;                // read-side swizzle

  auto stage = [&](int ti, int buf) {
#pragma unroll
    for (int i = 0; i < 2; ++i) {
      int row = i * 32 + w * 8 + srow;
      gload16(&Kh[(size_t)(ti * 64 + row) * D_ + sce], &Kl[buf][i * 2048 + w * 512]);
      gload16(&Vh[(size_t)row * T_ + ti * 64 + sce], &Vl[buf][i * 2048 + w * 512]);
    }
  };

  int NT = 2 * qt + 2;
  stage(0, 0);

  // Q fragments (B operand now): lane holds Q[q=c][d=ch*32+g*8+j]
  bf16x8 aq[2][2];
#pragma unroll
  for (int qf = 0; qf < 2; ++qf)
#pragma unroll
    for (int ch = 0; ch < 2; ++ch)
      aq[qf][ch] = *(const bf16x8*)&Qh[(size_t)(qbase + qf * 16 + c) * D_ + ch * 32 + g * 8];

  f32x4 o[2][4] = {};
  float mrun[2] = {-1e30f, -1e30f};
  float lrun[2] = {0.f, 0.f};

  __syncthreads();  // tile 0 staged

  for (int ti = 0; ti < NT; ++ti) {
    int cur = ti & 1;
    int kv0 = ti * 64;
    if (ti + 1 < NT) stage(ti + 1, cur ^ 1);

    // QK^T swapped: sf[qf][kb] = S[k=kv0+kb*16+g*4+r][q=qbase+qf*16+c]
    f32x4 sf[2][4];
#pragma unroll
    for (int kb = 0; kb < 4; ++kb) {
      bf16x8 bk0 = *(const bf16x8*)&Kl[cur][(kb * 16 + c) * 64 + ((g * 8) ^ cswz)];
      bf16x8 bk1 = *(const bf16x8*)&Kl[cur][(kb * 16 + c) * 64 + ((32 + g * 8) ^ cswz)];
#pragma unroll
      for (int qf = 0; qf < 2; ++qf) {
        f32x4 t = {};
        t = mfma16(bk0, aq[qf][0], t);
        t = mfma16(bk1, aq[qf][1], t);
        sf[qf][kb] = t;
      }
    }

    float s[2][4][4];
#pragma unroll
    for (int qf = 0; qf < 2; ++qf)
#pragma unroll
      for (int kb = 0; kb < 4; ++kb)
#pragma unroll
        for (int r = 0; r < 4; ++r) s[qf][kb][r] = sf[qf][kb][r] * 0.125f;
    if (kv0 + 63 > qbase) {  // wave-uniform; fully-masked tiles safe (exp->0)
#pragma unroll
      for (int qf = 0; qf < 2; ++qf)
#pragma unroll
        for (int kb = 0; kb < 4; ++kb)
#pragma unroll
          for (int r = 0; r < 4; ++r) {
            int qi = qbase + qf * 16 + c;
            int kv = kv0 + kb * 16 + g * 4 + r;
            if (kv > qi) s[qf][kb][r] = -1e30f;
          }
    }

    // online softmax: 16 k-values in-lane + 4-group (xor16/32) cross-lane reduce
#pragma unroll
    for (int qf = 0; qf < 2; ++qf) {
      float m01 = fmaxf(fmaxf(s[qf][0][0], s[qf][0][1]), fmaxf(s[qf][0][2], s[qf][0][3]));
      float m23 = fmaxf(fmaxf(s[qf][1][0], s[qf][1][1]), fmaxf(s[qf][1][2], s[qf][1][3]));
      float m45 = fmaxf(fmaxf(s[qf][2][0], s[qf][2][1]), fmaxf(s[qf][2][2], s[qf][2][3]));
      float m67 = fmaxf(fmaxf(s[qf][3][0], s[qf][3][1]), fmaxf(s[qf][3][2], s[qf][3][3]));
      float tm = fmaxf(fmaxf(m01, m23), fmaxf(m45, m67));
      tm = fmaxf(tm, __shfl_xor(tm, 16));
      tm = fmaxf(tm, __shfl_xor(tm, 32));
      float mn = fmaxf(mrun[qf], tm);
      float al = __expf(mrun[qf] - mn);
      mrun[qf] = mn;
      float asum = 0.f;
#pragma unroll
      for (int kb = 0; kb < 4; ++kb)
#pragma unroll
        for (int r = 0; r < 4; ++r) {
          float pv = __expf(s[qf][kb][r] - mn);
          s[qf][kb][r] = pv;
          asum += pv;
        }
      asum += __shfl_xor(asum, 16);
      asum += __shfl_xor(asum, 32);
      lrun[qf] = lrun[qf] * al + asum;
      if (l < 16) alw[w][qf][c] = al;
    }

    // P pack: lane owns P[k=kb*16+g*4+0..3][q=c] -> one b64 write per kb per qf
#pragma unroll
    for (int qf = 0; qf < 2; ++qf)
#pragma unroll
      for (int kb = 0; kb < 4; ++kb) {
        union { unsigned short u[4]; uint2 v2; } pk;
#pragma unroll
        for (int r = 0; r < 4; ++r) pk.u[r] = bfbits(s[qf][kb][r]);
        *(uint2*)&Pl[w][qf][c * LDP + kb * 16 + g * 4] = pk.v2;
      }

    // alpha transpose (c-indexed -> row g*4+r) and o rescale
#pragma unroll
    for (int qf = 0; qf < 2; ++qf) {
      f32x4 a4 = *(const f32x4*)&alw[w][qf][g * 4];
#pragma unroll
      for (int db = 0; db < 4; ++db)
#pragma unroll
        for (int r = 0; r < 4; ++r) o[qf][db][r] *= a4[r];
    }

    // V fragments (B operand): lane holds V^T[d=db*16+c][k=ck*32+g*8+j]
    bf16x8 bvv[4][2];
#pragma unroll
    for (int db = 0; db < 4; ++db)
#pragma unroll
      for (int ck = 0; ck < 2; ++ck)
        bvv[db][ck] = *(const bf16x8*)&Vl[cur][(db * 16 + c) * 64 + ((ck * 32 + g * 8) ^ cswz)];

    // PV: A-frag = P[q=c][k=ch*32+g*8+j] from Pl
#pragma unroll
    for (int qf = 0; qf < 2; ++qf) {
      bf16x8 pa0 = *(const bf16x8*)&Pl[w][qf][c * LDP + g * 8];
      bf16x8 pa1 = *(const bf16x8*)&Pl[w][qf][c * LDP + 32 + g * 8];
#pragma unroll
      for (int db = 0; db < 4; ++db) {
        o[qf][db] = mfma16(pa0, bvv[db][0], o[qf][db]);
        o[qf][db] = mfma16(pa1, bvv[db][1], o[qf][db]);
      }
    }
    __syncthreads();  // next tile staged + all waves done with cur
  }

  // epilogue: inv = 1/l transposed to row-index, then store
#pragma unroll
  for (int qf = 0; qf < 2; ++qf)
    if (l < 16) alw[w][qf][c] = 1.0f / lrun[qf];
  int b_ = bh >> 4, hh = bh & 15;
#pragma unroll
  for (int qf = 0; qf < 2; ++qf) {
    f32x4 i4 = *(const f32x4*)&alw[w][qf][g * 4];
#pragma unroll
    for (int r = 0; r < 4; ++r)
#pragma unroll
      for (int db = 0; db < 4; ++db)
        ctx[(size_t)(b_ * T_ + qbase + qf * 16 + g * 4 + r) * C_ + hh * D_ + db * 16 + c] =
            __float2bfloat16(o[qf][db][r] * i4[r]);
  }
}

extern "C" void kernel_launch(void* const* d_in, const int* in_sizes, int n_in, void* d_out,
                              int out_size, void* d_ws, size_t ws_size, hipStream_t stream) {
  const float* x = (const float*)d_in[0];
  const float* anw = (const float*)d_in[2];
  const float* mnw = (const float*)d_in[3];
  const float* q_w = (const float*)d_in[4];
  const float* q_b = (const float*)d_in[5];
  const float* k_w = (const float*)d_in[6];
  const float* k_b = (const float*)d_in[7];
  const float* v_w = (const float*)d_in[8];
  const float* v_b = (const float*)d_in[9];
  const float* o_w = (const float*)d_in[10];
  const float* o_b = (const float*)d_in[11];
  const float* w1 = (const float*)d_in[12];
  const float* b1 = (const float*)d_in[13];
  const float* w2 = (const float*)d_in[14];
  const float* b2 = (const float*)d_in[15];
  float* out = (float*)d_out;
  char* ws = (char*)d_ws;

  bf16* qkvT = (bf16*)(ws + 0);          // 6 MB [3072][1024]; dead after QKV gemm
  bf16* owT = (bf16*)(ws + 6291456);     // 2 MB; dead after o-proj
  bf16* w1T = (bf16*)(ws + 8388608);     // 8 MB
  bf16* w2T = (bf16*)(ws + 16777216);    // 8 MB
  bf16* h = (bf16*)(ws + 25165824);      // 8 MB  (also m)
  bf16* qb = (bf16*)(ws + 33554432);     // 8 MB
  bf16* kb = (bf16*)(ws + 41943040);     // 8 MB
  bf16* vtb = (bf16*)(ws + 58720256);    // 8 MB  V^T (B,H,D,T), by QKV EPI0
  bf16* ctx = (bf16*)(ws + 67108864);    // 8 MB
  float* x2 = (float*)(ws + 33554432);   // 16 MB over qb+kb (dead after attention)
  bf16* m = h;                           // reuse
  bf16* hid = (bf16*)(ws + 50331648);    // 32 MB, ends 83886080
  float* qkvb = (float*)(ws + 75497472); // 12 KB (inside hid span; dead before MLP1)
  float* p1 = (float*)(ws + 0);          // 16 MB MLP2 split-K partial

  cvt_transpose<<<dim3(32, 32), 256, 0, stream>>>(q_w, qkvT, 1024, 1024);
  cvt_transpose<<<dim3(32, 32), 256, 0, stream>>>(k_w, qkvT + 1048576, 1024, 1024);
  cvt_transpose<<<dim3(32, 32), 256, 0, stream>>>(v_w, qkvT + 2097152, 1024, 1024);
  cvt_transpose<<<dim3(32, 32), 256, 0, stream>>>(o_w, owT, 1024, 1024);
  cvt_transpose<<<dim3(128, 32), 256, 0, stream>>>(w1, w1T, 1024, 4096);
  cvt_transpose<<<dim3(32, 128), 256, 0, stream>>>(w2, w2T, 4096, 1024);
  pack_bias<<<12, 256, 0, stream>>>(q_b, k_b, v_b, qkvb);

  rmsnorm_kernel<<<4096, 256, 0, stream>>>(x, anw, h);

  gemm_kernel<0, 0, 1><<<dim3(24, 32), 256, 0, stream>>>(h, qkvT, qkvb, qb, out, nullptr,
                                                         vtb, nullptr, 4096, 3072, 1024);

  attn_kernel<<<512, 256, 0, stream>>>(qb, kb, vtb, ctx);

  gemm_kernel<1, 1, 1><<<dim3(8, 32), 256, 0, stream>>>(ctx, owT, o_b, nullptr, x2, x,
                                                        nullptr, nullptr, 4096, 1024, 1024);

  rmsnorm_kernel<<<4096, 256, 0, stream>>>(x2, mnw, m);

  gemm_kernel<2, 0, 1><<<dim3(32, 32), 256, 0, stream>>>(m, w1T, b1, hid, nullptr, nullptr,
                                                         nullptr, nullptr, 4096, 4096, 1024);
  gemm_kernel<1, 1, 2><<<dim3(8, 32, 2), 256, 0, stream>>>(hid, w2T, b2, nullptr, out, x2,
                                                           nullptr, p1, 4096, 1024, 4096);
  addp_kernel<<<2048, 256, 0, stream>>>(out, p1, 1048576);
}

// Round 9
// 309.316 us; speedup vs baseline: 1.1817x; 1.1031x over previous
//
#include <hip/hip_runtime.h>
#include <hip/hip_bf16.h>

// Transformer block fwd (B=2,T=2048,C=1024,H=16,D=64,HID=4096), bf16 MFMA compute.
// Round 9 (= R8 + compile fix): QKV + MLP1 on 256^2-tile 8-wave 2-phase GEMM with
//          granule-XOR LDS swizzle (both-sides) + XCD swizzle. Attn as R7.

#define B_ 2
#define T_ 2048
#define C_ 1024
#define H_ 16
#define D_ 64
#define HID_ 4096
#define M_ 4096  // B*T

typedef __bf16 bf16x8 __attribute__((ext_vector_type(8)));
typedef float f32x4 __attribute__((ext_vector_type(4)));
using bf16 = __hip_bfloat16;

static __device__ __forceinline__ f32x4 mfma16(bf16x8 a, bf16x8 b, f32x4 c) {
  return __builtin_amdgcn_mfma_f32_16x16x32_bf16(a, b, c, 0, 0, 0);
}

// async global->LDS, 16B per lane; LDS dest = wave-uniform base + lane*16
static __device__ __forceinline__ void gload16(const bf16* g, bf16* l) {
  __builtin_amdgcn_global_load_lds(
      (const __attribute__((address_space(1))) unsigned int*)g,
      (__attribute__((address_space(3))) unsigned int*)l, 16, 0, 0);
}

static __device__ __forceinline__ unsigned short bfbits(float x) {
  __hip_bfloat16 h = __float2bfloat16(x);
  return *(unsigned short*)&h;
}

// ---- weight convert + transpose: in f32 [K][N] -> out bf16 [N][K] ----
__global__ __launch_bounds__(256) void cvt_transpose(const float* __restrict__ in,
                                                     bf16* __restrict__ out, int K, int N) {
  __shared__ float tile[32][33];
  int tid = threadIdx.x, tx = tid & 31, ty = tid >> 5;
  int n0 = blockIdx.x * 32, k0 = blockIdx.y * 32;
#pragma unroll
  for (int i = 0; i < 4; ++i) {
    int r = ty + i * 8;
    tile[r][tx] = in[(size_t)(k0 + r) * N + n0 + tx];
  }
  __syncthreads();
#pragma unroll
  for (int i = 0; i < 4; ++i) {
    int r = ty + i * 8;
    out[(size_t)(n0 + r) * K + k0 + tx] = __float2bfloat16(tile[tx][r]);
  }
}

// ---- pack q/k/v bias into one 3072 vector ----
__global__ __launch_bounds__(256) void pack_bias(const float* __restrict__ q,
                                                 const float* __restrict__ k,
                                                 const float* __restrict__ v,
                                                 float* __restrict__ o) {
  int i = blockIdx.x * 256 + threadIdx.x;
  o[i] = i < 1024 ? q[i] : (i < 2048 ? k[i - 1024] : v[i - 2048]);
}

// ---- RMSNorm: x f32 [rows][1024] -> out bf16 ----
__global__ __launch_bounds__(256) void rmsnorm_kernel(const float* __restrict__ x,
                                                      const float* __restrict__ w,
                                                      bf16* __restrict__ out) {
  int row = blockIdx.x, tid = threadIdx.x;
  float4 v = ((const float4*)(x + (size_t)row * C_))[tid];
  float ss = v.x * v.x + v.y * v.y + v.z * v.z + v.w * v.w;
#pragma unroll
  for (int d = 1; d < 64; d <<= 1) ss += __shfl_xor(ss, d);
  __shared__ float wsum[4];
  if ((tid & 63) == 0) wsum[tid >> 6] = ss;
  __syncthreads();
  float tot = wsum[0] + wsum[1] + wsum[2] + wsum[3];
  float r = rsqrtf(tot * (1.0f / C_) + 1e-5f);
  float4 wv = ((const float4*)w)[tid];
  bf16* o = out + (size_t)row * C_ + tid * 4;
  o[0] = __float2bfloat16(v.x * wv.x * r);
  o[1] = __float2bfloat16(v.y * wv.y * r);
  o[2] = __float2bfloat16(v.z * wv.z * r);
  o[3] = __float2bfloat16(v.w * wv.w * r);
}

// ---- out[i] += p[i], float4 grid-stride ----
__global__ __launch_bounds__(256) void addp_kernel(float* __restrict__ out,
                                                   const float* __restrict__ p, int n4) {
  int i = blockIdx.x * 256 + threadIdx.x;
  int stride = gridDim.x * 256;
  for (; i < n4; i += stride) {
    float4 a = ((const float4*)out)[i];
    float4 b = ((const float4*)p)[i];
    a.x += b.x; a.y += b.y; a.z += b.z; a.w += b.w;
    ((float4*)out)[i] = a;
  }
}

// ---- 256^2-tile GEMM: C[M,N] = A[M,K] @ Bt[N,K]^T + bias. 8 waves (2Mx4N), BK=64.
// 2-phase double-buffer (stage issued before compute, one barrier/K-tile).
// LDS reads swizzled: granule ^= (row&7); global_load_lds source pre-swizzled (involution).
// EPI 0: fused-QKV scatter. EPI 2: bf16 out = gelu(acc+bias).
template <int EPI>
__global__ __launch_bounds__(512, 2) void gemm256_kernel(
    const bf16* __restrict__ A, const bf16* __restrict__ Bt, const float* __restrict__ bias,
    bf16* __restrict__ bfout, float* __restrict__ fout, bf16* __restrict__ vtb,
    int M, int N, int K) {
  __shared__ bf16 As[2][256 * 64];
  __shared__ bf16 Bs[2][256 * 64];
  int tid = threadIdx.x, wid = tid >> 6, l = tid & 63, g = l >> 4, c = l & 15;
  int wm = wid >> 2, wn = wid & 3;
  // bijective XCD-chunk swizzle (nwg % 8 == 0)
  int nwg = gridDim.x * gridDim.y;
  int bidl = blockIdx.y * gridDim.x + blockIdx.x;
  int wgid = (bidl & 7) * (nwg >> 3) + (bidl >> 3);
  int bx = wgid % gridDim.x, by = wgid / gridDim.x;
  int m0 = by * 256, n0 = bx * 256;
  int NT = K >> 6;
  int srow = l >> 3;               // row within 8-row chunk
  int sgr = (l & 7) ^ srow;        // pre-swizzled source granule (involution w/ read)

  auto stage = [&](int t, int buf) {
#pragma unroll
    for (int j = 0; j < 4; ++j) {
      int q = (wid << 2) + j;      // 32 chunks of 8 rows x 64 cols
      gload16(A + (size_t)(m0 + q * 8 + srow) * K + t * 64 + sgr * 8, &As[buf][q * 512]);
      gload16(Bt + (size_t)(n0 + q * 8 + srow) * K + t * 64 + sgr * 8, &Bs[buf][q * 512]);
    }
  };

  f32x4 acc[8][4] = {};
  stage(0, 0);
  __syncthreads();
  for (int t = 0; t < NT; ++t) {
    int cur = t & 1;
    if (t + 1 < NT) stage(t + 1, cur ^ 1);  // issue BEFORE compute; hides under MFMA
#pragma unroll
    for (int kk = 0; kk < 2; ++kk) {
      bf16x8 bfr[4];
#pragma unroll
      for (int nf = 0; nf < 4; ++nf) {
        int row = wn * 64 + nf * 16 + c;
        bfr[nf] = *(const bf16x8*)&Bs[cur][row * 64 + (((kk * 4 + g) ^ (c & 7)) << 3)];
      }
#pragma unroll
      for (int mf = 0; mf < 8; ++mf) {
        int row = wm * 128 + mf * 16 + c;
        bf16x8 af = *(const bf16x8*)&As[cur][row * 64 + (((kk * 4 + g) ^ (c & 7)) << 3)];
#pragma unroll
        for (int nf = 0; nf < 4; ++nf) acc[mf][nf] = mfma16(af, bfr[nf], acc[mf][nf]);
      }
    }
    __syncthreads();  // drains vmcnt -> next tile staged; all waves done with cur
  }

#pragma unroll
  for (int mf = 0; mf < 8; ++mf) {
#pragma unroll
    for (int nf = 0; nf < 4; ++nf) {
      int gn = n0 + wn * 64 + nf * 16 + c;
      float bv = bias[gn];
#pragma unroll
      for (int r = 0; r < 4; ++r) {
        int gm = m0 + wm * 128 + mf * 16 + g * 4 + r;
        float v = acc[mf][nf][r] + bv;
        if (EPI == 0) {
          int part = gn >> 10, wi = gn & 1023, hh = wi >> 6, d = wi & 63;
          int b_ = gm >> 11, t = gm & 2047;
          size_t idx = ((size_t)(b_ * H_ + hh) * T_ + t) * D_ + d;
          if (part == 2) {
            vtb[((size_t)(b_ * H_ + hh) * D_ + d) * T_ + t] = __float2bfloat16(v);
            fout[(size_t)2 * 4194304 + idx] = v;
          } else {
            bfout[(size_t)part * 4194304 + idx] = __float2bfloat16(v);
            if (part) fout[(size_t)part * 4194304 + idx] = v;
          }
        } else {
          float gl = 0.5f * v * (1.0f + erff(v * 0.70710678118f));
          bfout[(size_t)gm * N + gn] = __float2bfloat16(gl);
        }
      }
    }
  }
}

// ---- 128^2 GEMM (o-proj / MLP2 split-K): as R7 ----
template <int EPI, int DBUF, int SK>
__global__ __launch_bounds__(256) void gemm_kernel(
    const bf16* __restrict__ A, const bf16* __restrict__ Bt, const float* __restrict__ bias,
    bf16* __restrict__ bfout, float* __restrict__ fout, const float* __restrict__ res,
    float* __restrict__ paux, int M, int N, int K) {
  __shared__ bf16 Al[(DBUF ? 2 : 1) * 128 * 64];
  __shared__ bf16 Bl[(DBUF ? 2 : 1) * 128 * 64];
  int tid = threadIdx.x, w = tid >> 6, l = tid & 63;
  int g = l >> 4, c = l & 15;
  int nwg = gridDim.x * gridDim.y;
  int bidl = blockIdx.y * gridDim.x + blockIdx.x;
  int wgid = (bidl & 7) * (nwg >> 3) + (bidl >> 3);
  int bx = wgid % gridDim.x, by = wgid / gridDim.x;
  int m0 = by * 128, n0 = bx * 128;
  int wm = (w >> 1) * 64, wn = (w & 1) * 64;
  int Kc = K / SK;
  int kbase = (SK > 1) ? (int)blockIdx.z * Kc : 0;
  int KT = Kc >> 6;
  int lrow = l >> 3, lcol = (l & 7) * 8;

  const bf16* gA = A + (size_t)(m0 + w * 32 + lrow) * K + kbase + lcol;
  const bf16* gB = Bt + (size_t)(n0 + w * 32 + lrow) * K + kbase + lcol;

  auto stage = [&](int kt, int buf) {
#pragma unroll
    for (int i = 0; i < 4; ++i) {
      gload16(gA + (size_t)i * 8 * K + kt * 64, Al + buf * 8192 + (w * 4 + i) * 512);
      gload16(gB + (size_t)i * 8 * K + kt * 64, Bl + buf * 8192 + (w * 4 + i) * 512);
    }
  };
  auto compute = [&](int buf, f32x4 (&acc)[4][4]) {
#pragma unroll
    for (int ch = 0; ch < 2; ++ch) {
      bf16x8 af[4], bfr[4];
#pragma unroll
      for (int f = 0; f < 4; ++f)
        af[f] = *(const bf16x8*)&Al[buf * 8192 + (wm + f * 16 + c) * 64 + ch * 32 + g * 8];
#pragma unroll
      for (int f = 0; f < 4; ++f)
        bfr[f] = *(const bf16x8*)&Bl[buf * 8192 + (wn + f * 16 + c) * 64 + ch * 32 + g * 8];
#pragma unroll
      for (int mf = 0; mf < 4; ++mf)
#pragma unroll
        for (int nf = 0; nf < 4; ++nf) acc[mf][nf] = mfma16(af[mf], bfr[nf], acc[mf][nf]);
    }
  };

  f32x4 acc[4][4] = {};
  if (DBUF) {
    stage(0, 0);
    __syncthreads();
    for (int kt = 0; kt < KT; ++kt) {
      int cur = kt & 1;
      if (kt + 1 < KT) stage(kt + 1, cur ^ 1);
      compute(cur, acc);
      __syncthreads();
    }
  } else {
    for (int kt = 0; kt < KT; ++kt) {
      stage(kt, 0);
      __syncthreads();
      compute(0, acc);
      __syncthreads();
    }
  }

#pragma unroll
  for (int mf = 0; mf < 4; ++mf) {
#pragma unroll
    for (int nf = 0; nf < 4; ++nf) {
      int gn = n0 + wn + nf * 16 + c;
      float bv = bias ? bias[gn] : 0.f;
#pragma unroll
      for (int r = 0; r < 4; ++r) {
        int gm = m0 + wm + mf * 16 + g * 4 + r;
        float vr = acc[mf][nf][r];
        float v = vr + bv;
        if (SK > 1 && blockIdx.z > 0) {
          paux[(size_t)gm * N + gn] = vr;
        } else if (EPI == 1) {
          size_t idx = (size_t)gm * N + gn;
          fout[idx] = v + res[idx];
        } else {
          size_t idx = (size_t)gm * N + gn;
          float gl = 0.5f * v * (1.0f + erff(v * 0.70710678118f));
          bfout[idx] = __float2bfloat16(gl);
        }
      }
    }
  }
}

// ---- Flash attention (causal): shared-LDS KV staging (dbuf), SWAPPED QK^T (as R7) ----
__global__ __launch_bounds__(256, 2) void attn_kernel(const bf16* __restrict__ Q,
                                                      const bf16* __restrict__ Kb,
                                                      const bf16* __restrict__ Vt,
                                                      bf16* __restrict__ ctx) {
  constexpr int LDP = 72;
  __shared__ bf16 Kl[2][64 * 64];
  __shared__ bf16 Vl[2][64 * 64];
  __shared__ bf16 Pl[4][2][16 * LDP];
  __shared__ float alw[4][2][16];
  int tid = threadIdx.x, w = tid >> 6, l = tid & 63, g = l >> 4, c = l & 15;
  int bid = blockIdx.x;
  int qt = 15 - (bid >> 5);
  int bh = bid & 31;
  int qbase = qt * 128 + w * 32;
  const bf16* Qh = Q + (size_t)bh * T_ * D_;
  const bf16* Kh = Kb + (size_t)bh * T_ * D_;
  const bf16* Vh = Vt + (size_t)bh * T_ * D_;

  int srow = l >> 3;
  int sce = ((l & 7) * 8) ^ (srow << 3);
  int cswz = (c & 7) << 3;

  auto stage = [&](int ti, int buf) {
#pragma unroll
    for (int i = 0; i < 2; ++i) {
      int row = i * 32 + w * 8 + srow;
      gload16(&Kh[(size_t)(ti * 64 + row) * D_ + sce], &Kl[buf][i * 2048 + w * 512]);
      gload16(&Vh[(size_t)row * T_ + ti * 64 + sce], &Vl[buf][i * 2048 + w * 512]);
    }
  };

  int NT = 2 * qt + 2;
  stage(0, 0);

  bf16x8 aq[2][2];
#pragma unroll
  for (int qf = 0; qf < 2; ++qf)
#pragma unroll
    for (int ch = 0; ch < 2; ++ch)
      aq[qf][ch] = *(const bf16x8*)&Qh[(size_t)(qbase + qf * 16 + c) * D_ + ch * 32 + g * 8];

  f32x4 o[2][4] = {};
  float mrun[2] = {-1e30f, -1e30f};
  float lrun[2] = {0.f, 0.f};

  __syncthreads();

  for (int ti = 0; ti < NT; ++ti) {
    int cur = ti & 1;
    int kv0 = ti * 64;
    if (ti + 1 < NT) stage(ti + 1, cur ^ 1);

    f32x4 sf[2][4];
#pragma unroll
    for (int kb = 0; kb < 4; ++kb) {
      bf16x8 bk0 = *(const bf16x8*)&Kl[cur][(kb * 16 + c) * 64 + ((g * 8) ^ cswz)];
      bf16x8 bk1 = *(const bf16x8*)&Kl[cur][(kb * 16 + c) * 64 + ((32 + g * 8) ^ cswz)];
#pragma unroll
      for (int qf = 0; qf < 2; ++qf) {
        f32x4 t = {};
        t = mfma16(bk0, aq[qf][0], t);
        t = mfma16(bk1, aq[qf][1], t);
        sf[qf][kb] = t;
      }
    }

    float s[2][4][4];
#pragma unroll
    for (int qf = 0; qf < 2; ++qf)
#pragma unroll
      for (int kb = 0; kb < 4; ++kb)
#pragma unroll
        for (int r = 0; r < 4; ++r) s[qf][kb][r] = sf[qf][kb][r] * 0.125f;
    if (kv0 + 63 > qbase) {
#pragma unroll
      for (int qf = 0; qf < 2; ++qf)
#pragma unroll
        for (int kb = 0; kb < 4; ++kb)
#pragma unroll
          for (int r = 0; r < 4; ++r) {
            int qi = qbase + qf * 16 + c;
            int kv = kv0 + kb * 16 + g * 4 + r;
            if (kv > qi) s[qf][kb][r] = -1e30f;
          }
    }

#pragma unroll
    for (int qf = 0; qf < 2; ++qf) {
      float m01 = fmaxf(fmaxf(s[qf][0][0], s[qf][0][1]), fmaxf(s[qf][0][2], s[qf][0][3]));
      float m23 = fmaxf(fmaxf(s[qf][1][0], s[qf][1][1]), fmaxf(s[qf][1][2], s[qf][1][3]));
      float m45 = fmaxf(fmaxf(s[qf][2][0], s[qf][2][1]), fmaxf(s[qf][2][2], s[qf][2][3]));
      float m67 = fmaxf(fmaxf(s[qf][3][0], s[qf][3][1]), fmaxf(s[qf][3][2], s[qf][3][3]));
      float tm = fmaxf(fmaxf(m01, m23), fmaxf(m45, m67));
      tm = fmaxf(tm, __shfl_xor(tm, 16));
      tm = fmaxf(tm, __shfl_xor(tm, 32));
      float mn = fmaxf(mrun[qf], tm);
      float al = __expf(mrun[qf] - mn);
      mrun[qf] = mn;
      float asum = 0.f;
#pragma unroll
      for (int kb = 0; kb < 4; ++kb)
#pragma unroll
        for (int r = 0; r < 4; ++r) {
          float pv = __expf(s[qf][kb][r] - mn);
          s[qf][kb][r] = pv;
          asum += pv;
        }
      asum += __shfl_xor(asum, 16);
      asum += __shfl_xor(asum, 32);
      lrun[qf] = lrun[qf] * al + asum;
      if (l < 16) alw[w][qf][c] = al;
    }

#pragma unroll
    for (int qf = 0; qf < 2; ++qf)
#pragma unroll
      for (int kb = 0; kb < 4; ++kb) {
        union { unsigned short u[4]; uint2 v2; } pk;
#pragma unroll
        for (int r = 0; r < 4; ++r) pk.u[r] = bfbits(s[qf][kb][r]);
        *(uint2*)&Pl[w][qf][c * LDP + kb * 16 + g * 4] = pk.v2;
      }

#pragma unroll
    for (int qf = 0; qf < 2; ++qf) {
      f32x4 a4 = *(const f32x4*)&alw[w][qf][g * 4];
#pragma unroll
      for (int db = 0; db < 4; ++db)
#pragma unroll
        for (int r = 0; r < 4; ++r) o[qf][db][r] *= a4[r];
    }

    bf16x8 bvv[4][2];
#pragma unroll
    for (int db = 0; db < 4; ++db)
#pragma unroll
      for (int ck = 0; ck < 2; ++ck)
        bvv[db][ck] = *(const bf16x8*)&Vl[cur][(db * 16 + c) * 64 + ((ck * 32 + g * 8) ^ cswz)];

#pragma unroll
    for (int qf = 0; qf < 2; ++qf) {
      bf16x8 pa0 = *(const bf16x8*)&Pl[w][qf][c * LDP + g * 8];
      bf16x8 pa1 = *(const bf16x8*)&Pl[w][qf][c * LDP + 32 + g * 8];
#pragma unroll
      for (int db = 0; db < 4; ++db) {
        o[qf][db] = mfma16(pa0, bvv[db][0], o[qf][db]);
        o[qf][db] = mfma16(pa1, bvv[db][1], o[qf][db]);
      }
    }
    __syncthreads();
  }

#pragma unroll
  for (int qf = 0; qf < 2; ++qf)
    if (l < 16) alw[w][qf][c] = 1.0f / lrun[qf];
  int b_ = bh >> 4, hh = bh & 15;
#pragma unroll
  for (int qf = 0; qf < 2; ++qf) {
    f32x4 i4 = *(const f32x4*)&alw[w][qf][g * 4];
#pragma unroll
    for (int r = 0; r < 4; ++r)
#pragma unroll
      for (int db = 0; db < 4; ++db)
        ctx[(size_t)(b_ * T_ + qbase + qf * 16 + g * 4 + r) * C_ + hh * D_ + db * 16 + c] =
            __float2bfloat16(o[qf][db][r] * i4[r]);
  }
}

extern "C" void kernel_launch(void* const* d_in, const int* in_sizes, int n_in, void* d_out,
                              int out_size, void* d_ws, size_t ws_size, hipStream_t stream) {
  const float* x = (const float*)d_in[0];
  const float* anw = (const float*)d_in[2];
  const float* mnw = (const float*)d_in[3];
  const float* q_w = (const float*)d_in[4];
  const float* q_b = (const float*)d_in[5];
  const float* k_w = (const float*)d_in[6];
  const float* k_b = (const float*)d_in[7];
  const float* v_w = (const float*)d_in[8];
  const float* v_b = (const float*)d_in[9];
  const float* o_w = (const float*)d_in[10];
  const float* o_b = (const float*)d_in[11];
  const float* w1 = (const float*)d_in[12];
  const float* b1 = (const float*)d_in[13];
  const float* w2 = (const float*)d_in[14];
  const float* b2 = (const float*)d_in[15];
  float* out = (float*)d_out;
  char* ws = (char*)d_ws;

  bf16* qkvT = (bf16*)(ws + 0);          // 6 MB [3072][1024]; dead after QKV gemm
  bf16* owT = (bf16*)(ws + 6291456);     // 2 MB; dead after o-proj
  bf16* w1T = (bf16*)(ws + 8388608);     // 8 MB
  bf16* w2T = (bf16*)(ws + 16777216);    // 8 MB
  bf16* h = (bf16*)(ws + 25165824);      // 8 MB  (also m)
  bf16* qb = (bf16*)(ws + 33554432);     // 8 MB
  bf16* kb = (bf16*)(ws + 41943040);     // 8 MB
  bf16* vtb = (bf16*)(ws + 58720256);    // 8 MB  V^T (B,H,D,T), by QKV EPI0
  bf16* ctx = (bf16*)(ws + 67108864);    // 8 MB
  float* x2 = (float*)(ws + 33554432);   // 16 MB over qb+kb (dead after attention)
  bf16* m = h;                           // reuse
  bf16* hid = (bf16*)(ws + 50331648);    // 32 MB, ends 83886080
  float* qkvb = (float*)(ws + 75497472); // 12 KB (inside hid span; dead before MLP1)
  float* p1 = (float*)(ws + 0);          // 16 MB MLP2 split-K partial

  cvt_transpose<<<dim3(32, 32), 256, 0, stream>>>(q_w, qkvT, 1024, 1024);
  cvt_transpose<<<dim3(32, 32), 256, 0, stream>>>(k_w, qkvT + 1048576, 1024, 1024);
  cvt_transpose<<<dim3(32, 32), 256, 0, stream>>>(v_w, qkvT + 2097152, 1024, 1024);
  cvt_transpose<<<dim3(32, 32), 256, 0, stream>>>(o_w, owT, 1024, 1024);
  cvt_transpose<<<dim3(128, 32), 256, 0, stream>>>(w1, w1T, 1024, 4096);
  cvt_transpose<<<dim3(32, 128), 256, 0, stream>>>(w2, w2T, 4096, 1024);
  pack_bias<<<12, 256, 0, stream>>>(q_b, k_b, v_b, qkvb);

  rmsnorm_kernel<<<4096, 256, 0, stream>>>(x, anw, h);

  // fused QKV: C[4096][3072] on 256^2 tiles (192 blocks)
  gemm256_kernel<0><<<dim3(12, 16), 512, 0, stream>>>(h, qkvT, qkvb, qb, out, vtb,
                                                      4096, 3072, 1024);

  attn_kernel<<<512, 256, 0, stream>>>(qb, kb, vtb, ctx);

  gemm_kernel<1, 1, 1><<<dim3(8, 32), 256, 0, stream>>>(ctx, owT, o_b, nullptr, x2, x,
                                                        nullptr, 4096, 1024, 1024);

  rmsnorm_kernel<<<4096, 256, 0, stream>>>(x2, mnw, m);

  // MLP1 on 256^2 tiles (256 blocks, 1/CU)
  gemm256_kernel<2><<<dim3(16, 16), 512, 0, stream>>>(m, w1T, b1, hid, nullptr, nullptr,
                                                      4096, 4096, 1024);
  gemm_kernel<1, 1, 2><<<dim3(8, 32, 2), 256, 0, stream>>>(hid, w2T, b2, nullptr, out, x2,
                                                           p1, 4096, 1024, 4096);
  addp_kernel<<<2048, 256, 0, stream>>>(out, p1, 1048576);
}

// Round 10
// 299.926 us; speedup vs baseline: 1.2187x; 1.0313x over previous
//
#include <hip/hip_runtime.h>
#include <hip/hip_bf16.h>

// Transformer block fwd (B=2,T=2048,C=1024,H=16,D=64,HID=4096), bf16 MFMA compute.
// Round 10: counted-vmcnt + raw s_barrier (T4-lite) in both GEMM loops (prefetch
//           survives the barrier); granule-XOR LDS swizzle added to the 128^2 GEMM
//           (o-proj / MLP2). Attn as R7/R9.

#define B_ 2
#define T_ 2048
#define C_ 1024
#define H_ 16
#define D_ 64
#define HID_ 4096
#define M_ 4096  // B*T

typedef __bf16 bf16x8 __attribute__((ext_vector_type(8)));
typedef float f32x4 __attribute__((ext_vector_type(4)));
using bf16 = __hip_bfloat16;

// counted waits / raw barrier: own loads proven landed via vmcnt(N) BEFORE s_barrier;
// barrier then guarantees all waves'. "memory" clobber orders all LDS/VMEM ops.
#define WAIT_VM(N) asm volatile("s_waitcnt vmcnt(" #N ")" ::: "memory")
#define SBAR() asm volatile("s_barrier" ::: "memory")

static __device__ __forceinline__ f32x4 mfma16(bf16x8 a, bf16x8 b, f32x4 c) {
  return __builtin_amdgcn_mfma_f32_16x16x32_bf16(a, b, c, 0, 0, 0);
}

// async global->LDS, 16B per lane; LDS dest = wave-uniform base + lane*16
static __device__ __forceinline__ void gload16(const bf16* g, bf16* l) {
  __builtin_amdgcn_global_load_lds(
      (const __attribute__((address_space(1))) unsigned int*)g,
      (__attribute__((address_space(3))) unsigned int*)l, 16, 0, 0);
}

static __device__ __forceinline__ unsigned short bfbits(float x) {
  __hip_bfloat16 h = __float2bfloat16(x);
  return *(unsigned short*)&h;
}

// ---- weight convert + transpose: in f32 [K][N] -> out bf16 [N][K] ----
__global__ __launch_bounds__(256) void cvt_transpose(const float* __restrict__ in,
                                                     bf16* __restrict__ out, int K, int N) {
  __shared__ float tile[32][33];
  int tid = threadIdx.x, tx = tid & 31, ty = tid >> 5;
  int n0 = blockIdx.x * 32, k0 = blockIdx.y * 32;
#pragma unroll
  for (int i = 0; i < 4; ++i) {
    int r = ty + i * 8;
    tile[r][tx] = in[(size_t)(k0 + r) * N + n0 + tx];
  }
  __syncthreads();
#pragma unroll
  for (int i = 0; i < 4; ++i) {
    int r = ty + i * 8;
    out[(size_t)(n0 + r) * K + k0 + tx] = __float2bfloat16(tile[tx][r]);
  }
}

// ---- pack q/k/v bias into one 3072 vector ----
__global__ __launch_bounds__(256) void pack_bias(const float* __restrict__ q,
                                                 const float* __restrict__ k,
                                                 const float* __restrict__ v,
                                                 float* __restrict__ o) {
  int i = blockIdx.x * 256 + threadIdx.x;
  o[i] = i < 1024 ? q[i] : (i < 2048 ? k[i - 1024] : v[i - 2048]);
}

// ---- RMSNorm: x f32 [rows][1024] -> out bf16 ----
__global__ __launch_bounds__(256) void rmsnorm_kernel(const float* __restrict__ x,
                                                      const float* __restrict__ w,
                                                      bf16* __restrict__ out) {
  int row = blockIdx.x, tid = threadIdx.x;
  float4 v = ((const float4*)(x + (size_t)row * C_))[tid];
  float ss = v.x * v.x + v.y * v.y + v.z * v.z + v.w * v.w;
#pragma unroll
  for (int d = 1; d < 64; d <<= 1) ss += __shfl_xor(ss, d);
  __shared__ float wsum[4];
  if ((tid & 63) == 0) wsum[tid >> 6] = ss;
  __syncthreads();
  float tot = wsum[0] + wsum[1] + wsum[2] + wsum[3];
  float r = rsqrtf(tot * (1.0f / C_) + 1e-5f);
  float4 wv = ((const float4*)w)[tid];
  bf16* o = out + (size_t)row * C_ + tid * 4;
  o[0] = __float2bfloat16(v.x * wv.x * r);
  o[1] = __float2bfloat16(v.y * wv.y * r);
  o[2] = __float2bfloat16(v.z * wv.z * r);
  o[3] = __float2bfloat16(v.w * wv.w * r);
}

// ---- out[i] += p[i], float4 grid-stride ----
__global__ __launch_bounds__(256) void addp_kernel(float* __restrict__ out,
                                                   const float* __restrict__ p, int n4) {
  int i = blockIdx.x * 256 + threadIdx.x;
  int stride = gridDim.x * 256;
  for (; i < n4; i += stride) {
    float4 a = ((const float4*)out)[i];
    float4 b = ((const float4*)p)[i];
    a.x += b.x; a.y += b.y; a.z += b.z; a.w += b.w;
    ((float4*)out)[i] = a;
  }
}

// ---- 256^2-tile GEMM: 8 waves (2Mx4N), BK=64, dbuf, counted-vmcnt barriers.
// LDS granule-XOR swizzle both-sides. EPI 0: fused-QKV scatter. EPI 2: gelu.
template <int EPI>
__global__ __launch_bounds__(512, 2) void gemm256_kernel(
    const bf16* __restrict__ A, const bf16* __restrict__ Bt, const float* __restrict__ bias,
    bf16* __restrict__ bfout, float* __restrict__ fout, bf16* __restrict__ vtb,
    int M, int N, int K) {
  __shared__ bf16 As[2][256 * 64];
  __shared__ bf16 Bs[2][256 * 64];
  int tid = threadIdx.x, wid = tid >> 6, l = tid & 63, g = l >> 4, c = l & 15;
  int wm = wid >> 2, wn = wid & 3;
  // bijective XCD-chunk swizzle (nwg % 8 == 0)
  int nwg = gridDim.x * gridDim.y;
  int bidl = blockIdx.y * gridDim.x + blockIdx.x;
  int wgid = (bidl & 7) * (nwg >> 3) + (bidl >> 3);
  int bx = wgid % gridDim.x, by = wgid / gridDim.x;
  int m0 = by * 256, n0 = bx * 256;
  int NT = K >> 6;
  int srow = l >> 3;               // row within 8-row chunk
  int sgr = (l & 7) ^ srow;        // pre-swizzled source granule (involution w/ read)

  auto stage = [&](int t, int buf) {
#pragma unroll
    for (int j = 0; j < 4; ++j) {
      int q = (wid << 2) + j;      // 32 chunks of 8 rows x 64 cols; 8 gloads/thread total
      gload16(A + (size_t)(m0 + q * 8 + srow) * K + t * 64 + sgr * 8, &As[buf][q * 512]);
      gload16(Bt + (size_t)(n0 + q * 8 + srow) * K + t * 64 + sgr * 8, &Bs[buf][q * 512]);
    }
  };

  f32x4 acc[8][4] = {};
  stage(0, 0);
  for (int t = 0; t < NT; ++t) {
    int cur = t & 1;
    if (t + 1 < NT) {
      stage(t + 1, cur ^ 1);  // 8 loads in flight across the barrier
      WAIT_VM(8);             // own tile-t loads landed (t+1's may remain)
    } else {
      WAIT_VM(0);
    }
    SBAR();
    __builtin_amdgcn_s_setprio(1);
#pragma unroll
    for (int kk = 0; kk < 2; ++kk) {
      bf16x8 bfr[4];
#pragma unroll
      for (int nf = 0; nf < 4; ++nf) {
        int row = wn * 64 + nf * 16 + c;
        bfr[nf] = *(const bf16x8*)&Bs[cur][row * 64 + (((kk * 4 + g) ^ (c & 7)) << 3)];
      }
#pragma unroll
      for (int mf = 0; mf < 8; ++mf) {
        int row = wm * 128 + mf * 16 + c;
        bf16x8 af = *(const bf16x8*)&As[cur][row * 64 + (((kk * 4 + g) ^ (c & 7)) << 3)];
#pragma unroll
        for (int nf = 0; nf < 4; ++nf) acc[mf][nf] = mfma16(af, bfr[nf], acc[mf][nf]);
      }
    }
    __builtin_amdgcn_s_setprio(0);
    __builtin_amdgcn_sched_barrier(0);  // keep MFMA + lgkm waits before the barrier
    SBAR();
  }

#pragma unroll
  for (int mf = 0; mf < 8; ++mf) {
#pragma unroll
    for (int nf = 0; nf < 4; ++nf) {
      int gn = n0 + wn * 64 + nf * 16 + c;
      float bv = bias[gn];
#pragma unroll
      for (int r = 0; r < 4; ++r) {
        int gm = m0 + wm * 128 + mf * 16 + g * 4 + r;
        float v = acc[mf][nf][r] + bv;
        if (EPI == 0) {
          int part = gn >> 10, wi = gn & 1023, hh = wi >> 6, d = wi & 63;
          int b_ = gm >> 11, t = gm & 2047;
          size_t idx = ((size_t)(b_ * H_ + hh) * T_ + t) * D_ + d;
          if (part == 2) {
            vtb[((size_t)(b_ * H_ + hh) * D_ + d) * T_ + t] = __float2bfloat16(v);
            fout[(size_t)2 * 4194304 + idx] = v;
          } else {
            bfout[(size_t)part * 4194304 + idx] = __float2bfloat16(v);
            if (part) fout[(size_t)part * 4194304 + idx] = v;
          }
        } else {
          float gl = 0.5f * v * (1.0f + erff(v * 0.70710678118f));
          bfout[(size_t)gm * N + gn] = __float2bfloat16(gl);
        }
      }
    }
  }
}

// ---- 128^2 GEMM (o-proj / MLP2 split-K): dbuf + counted-vmcnt + granule swizzle ----
template <int EPI, int DBUF, int SK>
__global__ __launch_bounds__(256) void gemm_kernel(
    const bf16* __restrict__ A, const bf16* __restrict__ Bt, const float* __restrict__ bias,
    bf16* __restrict__ bfout, float* __restrict__ fout, const float* __restrict__ res,
    float* __restrict__ paux, int M, int N, int K) {
  __shared__ bf16 Al[(DBUF ? 2 : 1) * 128 * 64];
  __shared__ bf16 Bl[(DBUF ? 2 : 1) * 128 * 64];
  int tid = threadIdx.x, w = tid >> 6, l = tid & 63;
  int g = l >> 4, c = l & 15;
  int nwg = gridDim.x * gridDim.y;
  int bidl = blockIdx.y * gridDim.x + blockIdx.x;
  int wgid = (bidl & 7) * (nwg >> 3) + (bidl >> 3);
  int bx = wgid % gridDim.x, by = wgid / gridDim.x;
  int m0 = by * 128, n0 = bx * 128;
  int wm = (w >> 1) * 64, wn = (w & 1) * 64;
  int Kc = K / SK;
  int kbase = (SK > 1) ? (int)blockIdx.z * Kc : 0;
  int KT = Kc >> 6;
  int lrow = l >> 3;
  int sgr = (l & 7) ^ lrow;  // pre-swizzled source granule (involution w/ read)

  const bf16* gA = A + (size_t)(m0 + w * 32 + lrow) * K + kbase + sgr * 8;
  const bf16* gB = Bt + (size_t)(n0 + w * 32 + lrow) * K + kbase + sgr * 8;

  auto stage = [&](int kt, int buf) {
#pragma unroll
    for (int i = 0; i < 4; ++i) {
      gload16(gA + (size_t)i * 8 * K + kt * 64, Al + buf * 8192 + (w * 4 + i) * 512);
      gload16(gB + (size_t)i * 8 * K + kt * 64, Bl + buf * 8192 + (w * 4 + i) * 512);
    }
  };
  auto compute = [&](int buf, f32x4 (&acc)[4][4]) {
#pragma unroll
    for (int ch = 0; ch < 2; ++ch) {
      bf16x8 af[4], bfr[4];
#pragma unroll
      for (int f = 0; f < 4; ++f)
        af[f] = *(const bf16x8*)&Al[buf * 8192 + (wm + f * 16 + c) * 64 +
                                    (((ch * 4 + g) ^ (c & 7)) << 3)];
#pragma unroll
      for (int f = 0; f < 4; ++f)
        bfr[f] = *(const bf16x8*)&Bl[buf * 8192 + (wn + f * 16 + c) * 64 +
                                     (((ch * 4 + g) ^ (c & 7)) << 3)];
#pragma unroll
      for (int mf = 0; mf < 4; ++mf)
#pragma unroll
        for (int nf = 0; nf < 4; ++nf) acc[mf][nf] = mfma16(af[mf], bfr[nf], acc[mf][nf]);
    }
  };

  f32x4 acc[4][4] = {};
  if (DBUF) {
    stage(0, 0);
    for (int kt = 0; kt < KT; ++kt) {
      int cur = kt & 1;
      if (kt + 1 < KT) {
        stage(kt + 1, cur ^ 1);
        WAIT_VM(8);
      } else {
        WAIT_VM(0);
      }
      SBAR();
      __builtin_amdgcn_s_setprio(1);
      compute(cur, acc);
      __builtin_amdgcn_s_setprio(0);
      __builtin_amdgcn_sched_barrier(0);
      SBAR();
    }
  } else {
    for (int kt = 0; kt < KT; ++kt) {
      stage(kt, 0);
      __syncthreads();
      compute(0, acc);
      __syncthreads();
    }
  }

#pragma unroll
  for (int mf = 0; mf < 4; ++mf) {
#pragma unroll
    for (int nf = 0; nf < 4; ++nf) {
      int gn = n0 + wn + nf * 16 + c;
      float bv = bias ? bias[gn] : 0.f;
#pragma unroll
      for (int r = 0; r < 4; ++r) {
        int gm = m0 + wm + mf * 16 + g * 4 + r;
        float vr = acc[mf][nf][r];
        float v = vr + bv;
        if (SK > 1 && blockIdx.z > 0) {
          paux[(size_t)gm * N + gn] = vr;
        } else if (EPI == 1) {
          size_t idx = (size_t)gm * N + gn;
          fout[idx] = v + res[idx];
        } else {
          size_t idx = (size_t)gm * N + gn;
          float gl = 0.5f * v * (1.0f + erff(v * 0.70710678118f));
          bfout[idx] = __float2bfloat16(gl);
        }
      }
    }
  }
}

// ---- Flash attention (causal): shared-LDS KV staging (dbuf), SWAPPED QK^T (as R7) ----
__global__ __launch_bounds__(256, 2) void attn_kernel(const bf16* __restrict__ Q,
                                                      const bf16* __restrict__ Kb,
                                                      const bf16* __restrict__ Vt,
                                                      bf16* __restrict__ ctx) {
  constexpr int LDP = 72;
  __shared__ bf16 Kl[2][64 * 64];
  __shared__ bf16 Vl[2][64 * 64];
  __shared__ bf16 Pl[4][2][16 * LDP];
  __shared__ float alw[4][2][16];
  int tid = threadIdx.x, w = tid >> 6, l = tid & 63, g = l >> 4, c = l & 15;
  int bid = blockIdx.x;
  int qt = 15 - (bid >> 5);
  int bh = bid & 31;
  int qbase = qt * 128 + w * 32;
  const bf16* Qh = Q + (size_t)bh * T_ * D_;
  const bf16* Kh = Kb + (size_t)bh * T_ * D_;
  const bf16* Vh = Vt + (size_t)bh * T_ * D_;

  int srow = l >> 3;
  int sce = ((l & 7) * 8) ^ (srow << 3);
  int cswz = (c & 7) << 3;

  auto stage = [&](int ti, int buf) {
#pragma unroll
    for (int i = 0; i < 2; ++i) {
      int row = i * 32 + w * 8 + srow;
      gload16(&Kh[(size_t)(ti * 64 + row) * D_ + sce], &Kl[buf][i * 2048 + w * 512]);
      gload16(&Vh[(size_t)row * T_ + ti * 64 + sce], &Vl[buf][i * 2048 + w * 512]);
    }
  };

  int NT = 2 * qt + 2;
  stage(0, 0);

  bf16x8 aq[2][2];
#pragma unroll
  for (int qf = 0; qf < 2; ++qf)
#pragma unroll
    for (int ch = 0; ch < 2; ++ch)
      aq[qf][ch] = *(const bf16x8*)&Qh[(size_t)(qbase + qf * 16 + c) * D_ + ch * 32 + g * 8];

  f32x4 o[2][4] = {};
  float mrun[2] = {-1e30f, -1e30f};
  float lrun[2] = {0.f, 0.f};

  __syncthreads();

  for (int ti = 0; ti < NT; ++ti) {
    int cur = ti & 1;
    int kv0 = ti * 64;
    if (ti + 1 < NT) stage(ti + 1, cur ^ 1);

    f32x4 sf[2][4];
#pragma unroll
    for (int kb = 0; kb < 4; ++kb) {
      bf16x8 bk0 = *(const bf16x8*)&Kl[cur][(kb * 16 + c) * 64 + ((g * 8) ^ cswz)];
      bf16x8 bk1 = *(const bf16x8*)&Kl[cur][(kb * 16 + c) * 64 + ((32 + g * 8) ^ cswz)];
#pragma unroll
      for (int qf = 0; qf < 2; ++qf) {
        f32x4 t = {};
        t = mfma16(bk0, aq[qf][0], t);
        t = mfma16(bk1, aq[qf][1], t);
        sf[qf][kb] = t;
      }
    }

    float s[2][4][4];
#pragma unroll
    for (int qf = 0; qf < 2; ++qf)
#pragma unroll
      for (int kb = 0; kb < 4; ++kb)
#pragma unroll
        for (int r = 0; r < 4; ++r) s[qf][kb][r] = sf[qf][kb][r] * 0.125f;
    if (kv0 + 63 > qbase) {
#pragma unroll
      for (int qf = 0; qf < 2; ++qf)
#pragma unroll
        for (int kb = 0; kb < 4; ++kb)
#pragma unroll
          for (int r = 0; r < 4; ++r) {
            int qi = qbase + qf * 16 + c;
            int kv = kv0 + kb * 16 + g * 4 + r;
            if (kv > qi) s[qf][kb][r] = -1e30f;
          }
    }

#pragma unroll
    for (int qf = 0; qf < 2; ++qf) {
      float m01 = fmaxf(fmaxf(s[qf][0][0], s[qf][0][1]), fmaxf(s[qf][0][2], s[qf][0][3]));
      float m23 = fmaxf(fmaxf(s[qf][1][0], s[qf][1][1]), fmaxf(s[qf][1][2], s[qf][1][3]));
      float m45 = fmaxf(fmaxf(s[qf][2][0], s[qf][2][1]), fmaxf(s[qf][2][2], s[qf][2][3]));
      float m67 = fmaxf(fmaxf(s[qf][3][0], s[qf][3][1]), fmaxf(s[qf][3][2], s[qf][3][3]));
      float tm = fmaxf(fmaxf(m01, m23), fmaxf(m45, m67));
      tm = fmaxf(tm, __shfl_xor(tm, 16));
      tm = fmaxf(tm, __shfl_xor(tm, 32));
      float mn = fmaxf(mrun[qf], tm);
      float al = __expf(mrun[qf] - mn);
      mrun[qf] = mn;
      float asum = 0.f;
#pragma unroll
      for (int kb = 0; kb < 4; ++kb)
#pragma unroll
        for (int r = 0; r < 4; ++r) {
          float pv = __expf(s[qf][kb][r] - mn);
          s[qf][kb][r] = pv;
          asum += pv;
        }
      asum += __shfl_xor(asum, 16);
      asum += __shfl_xor(asum, 32);
      lrun[qf] = lrun[qf] * al + asum;
      if (l < 16) alw[w][qf][c] = al;
    }

#pragma unroll
    for (int qf = 0; qf < 2; ++qf)
#pragma unroll
      for (int kb = 0; kb < 4; ++kb) {
        union { unsigned short u[4]; uint2 v2; } pk;
#pragma unroll
        for (int r = 0; r < 4; ++r) pk.u[r] = bfbits(s[qf][kb][r]);
        *(uint2*)&Pl[w][qf][c * LDP + kb * 16 + g * 4] = pk.v2;
      }

#pragma unroll
    for (int qf = 0; qf < 2; ++qf) {
      f32x4 a4 = *(const f32x4*)&alw[w][qf][g * 4];
#pragma unroll
      for (int db = 0; db < 4; ++db)
#pragma unroll
        for (int r = 0; r < 4; ++r) o[qf][db][r] *= a4[r];
    }

    bf16x8 bvv[4][2];
#pragma unroll
    for (int db = 0; db < 4; ++db)
#pragma unroll
      for (int ck = 0; ck < 2; ++ck)
        bvv[db][ck] = *(const bf16x8*)&Vl[cur][(db * 16 + c) * 64 + ((ck * 32 + g * 8) ^ cswz)];

#pragma unroll
    for (int qf = 0; qf < 2; ++qf) {
      bf16x8 pa0 = *(const bf16x8*)&Pl[w][qf][c * LDP + g * 8];
      bf16x8 pa1 = *(const bf16x8*)&Pl[w][qf][c * LDP + 32 + g * 8];
#pragma unroll
      for (int db = 0; db < 4; ++db) {
        o[qf][db] = mfma16(pa0, bvv[db][0], o[qf][db]);
        o[qf][db] = mfma16(pa1, bvv[db][1], o[qf][db]);
      }
    }
    __syncthreads();
  }

#pragma unroll
  for (int qf = 0; qf < 2; ++qf)
    if (l < 16) alw[w][qf][c] = 1.0f / lrun[qf];
  int b_ = bh >> 4, hh = bh & 15;
#pragma unroll
  for (int qf = 0; qf < 2; ++qf) {
    f32x4 i4 = *(const f32x4*)&alw[w][qf][g * 4];
#pragma unroll
    for (int r = 0; r < 4; ++r)
#pragma unroll
      for (int db = 0; db < 4; ++db)
        ctx[(size_t)(b_ * T_ + qbase + qf * 16 + g * 4 + r) * C_ + hh * D_ + db * 16 + c] =
            __float2bfloat16(o[qf][db][r] * i4[r]);
  }
}

extern "C" void kernel_launch(void* const* d_in, const int* in_sizes, int n_in, void* d_out,
                              int out_size, void* d_ws, size_t ws_size, hipStream_t stream) {
  const float* x = (const float*)d_in[0];
  const float* anw = (const float*)d_in[2];
  const float* mnw = (const float*)d_in[3];
  const float* q_w = (const float*)d_in[4];
  const float* q_b = (const float*)d_in[5];
  const float* k_w = (const float*)d_in[6];
  const float* k_b = (const float*)d_in[7];
  const float* v_w = (const float*)d_in[8];
  const float* v_b = (const float*)d_in[9];
  const float* o_w = (const float*)d_in[10];
  const float* o_b = (const float*)d_in[11];
  const float* w1 = (const float*)d_in[12];
  const float* b1 = (const float*)d_in[13];
  const float* w2 = (const float*)d_in[14];
  const float* b2 = (const float*)d_in[15];
  float* out = (float*)d_out;
  char* ws = (char*)d_ws;

  bf16* qkvT = (bf16*)(ws + 0);          // 6 MB [3072][1024]; dead after QKV gemm
  bf16* owT = (bf16*)(ws + 6291456);     // 2 MB; dead after o-proj
  bf16* w1T = (bf16*)(ws + 8388608);     // 8 MB
  bf16* w2T = (bf16*)(ws + 16777216);    // 8 MB
  bf16* h = (bf16*)(ws + 25165824);      // 8 MB  (also m)
  bf16* qb = (bf16*)(ws + 33554432);     // 8 MB
  bf16* kb = (bf16*)(ws + 41943040);     // 8 MB
  bf16* vtb = (bf16*)(ws + 58720256);    // 8 MB  V^T (B,H,D,T), by QKV EPI0
  bf16* ctx = (bf16*)(ws + 67108864);    // 8 MB
  float* x2 = (float*)(ws + 33554432);   // 16 MB over qb+kb (dead after attention)
  bf16* m = h;                           // reuse
  bf16* hid = (bf16*)(ws + 50331648);    // 32 MB, ends 83886080
  float* qkvb = (float*)(ws + 75497472); // 12 KB (inside hid span; dead before MLP1)
  float* p1 = (float*)(ws + 0);          // 16 MB MLP2 split-K partial

  cvt_transpose<<<dim3(32, 32), 256, 0, stream>>>(q_w, qkvT, 1024, 1024);
  cvt_transpose<<<dim3(32, 32), 256, 0, stream>>>(k_w, qkvT + 1048576, 1024, 1024);
  cvt_transpose<<<dim3(32, 32), 256, 0, stream>>>(v_w, qkvT + 2097152, 1024, 1024);
  cvt_transpose<<<dim3(32, 32), 256, 0, stream>>>(o_w, owT, 1024, 1024);
  cvt_transpose<<<dim3(128, 32), 256, 0, stream>>>(w1, w1T, 1024, 4096);
  cvt_transpose<<<dim3(32, 128), 256, 0, stream>>>(w2, w2T, 4096, 1024);
  pack_bias<<<12, 256, 0, stream>>>(q_b, k_b, v_b, qkvb);

  rmsnorm_kernel<<<4096, 256, 0, stream>>>(x, anw, h);

  // fused QKV: C[4096][3072] on 256^2 tiles (192 blocks)
  gemm256_kernel<0><<<dim3(12, 16), 512, 0, stream>>>(h, qkvT, qkvb, qb, out, vtb,
                                                      4096, 3072, 1024);

  attn_kernel<<<512, 256, 0, stream>>>(qb, kb, vtb, ctx);

  gemm_kernel<1, 1, 1><<<dim3(8, 32), 256, 0, stream>>>(ctx, owT, o_b, nullptr, x2, x,
                                                        nullptr, 4096, 1024, 1024);

  rmsnorm_kernel<<<4096, 256, 0, stream>>>(x2, mnw, m);

  // MLP1 on 256^2 tiles (256 blocks, 1/CU)
  gemm256_kernel<2><<<dim3(16, 16), 512, 0, stream>>>(m, w1T, b1, hid, nullptr, nullptr,
                                                      4096, 4096, 1024);
  gemm_kernel<1, 1, 2><<<dim3(8, 32, 2), 256, 0, stream>>>(hid, w2T, b2, nullptr, out, x2,
                                                           p1, 4096, 1024, 4096);
  addp_kernel<<<2048, 256, 0, stream>>>(out, p1, 1048576);
}